// Round 1
// baseline (139.748 us; speedup 1.0000x reference)
//
#include <hip/hip_runtime.h>
#include <hip/hip_bf16.h>
#include <stdint.h>

#define B_ 4
#define N_ 2048
#define DIM_ 512
#define H_ 8
#define D_ 64
#define M_ (B_*N_)   // 8192

typedef unsigned short u16;
typedef short bf16x8 __attribute__((ext_vector_type(8)));
typedef float f32x4 __attribute__((ext_vector_type(4)));
typedef unsigned short u16x8 __attribute__((ext_vector_type(8)));
typedef unsigned short u16x4 __attribute__((ext_vector_type(4)));

__device__ __forceinline__ u16 f2bf(float f) {
  union { float f; uint32_t u; } v; v.f = f;
  uint32_t r = v.u + 0x7fffu + ((v.u >> 16) & 1u);
  return (u16)(r >> 16);
}

__device__ __forceinline__ void gload_lds16(const void* g, void* l) {
  __builtin_amdgcn_global_load_lds(
      (const __attribute__((address_space(1))) void*)g,
      (__attribute__((address_space(3))) void*)l, 16, 0, 0);
}

// ---------------- convert x -> bf16 row-major [8192][512] ----------------
__global__ __launch_bounds__(256) void k_convert_x(const float* __restrict__ x,
                                                   u16* __restrict__ xb) {
  int t = blockIdx.x * 256 + threadIdx.x;
  int e = t * 8;
  const float4* p = (const float4*)(x + e);
  float4 a = p[0], b = p[1];
  u16x8 o;
  o[0]=f2bf(a.x); o[1]=f2bf(a.y); o[2]=f2bf(a.z); o[3]=f2bf(a.w);
  o[4]=f2bf(b.x); o[5]=f2bf(b.y); o[6]=f2bf(b.z); o[7]=f2bf(b.w);
  *(u16x8*)(xb + e) = o;
}

// ---------------- convert Wq/Wk -> bf16 ----------------
__global__ __launch_bounds__(256) void k_convert_w(const float* __restrict__ Wq,
                                                   const float* __restrict__ Wk,
                                                   u16* __restrict__ wqb,
                                                   u16* __restrict__ wkb) {
  int t = blockIdx.x * 256 + threadIdx.x;
  int e = t * 8;
  const float* src; u16* dst; int off;
  if (e < DIM_*DIM_) { src = Wq; dst = wqb; off = e; }
  else               { src = Wk; dst = wkb; off = e - DIM_*DIM_; }
  const float4* p = (const float4*)(src + off);
  float4 a = p[0], b = p[1];
  u16x8 o;
  o[0]=f2bf(a.x); o[1]=f2bf(a.y); o[2]=f2bf(a.z); o[3]=f2bf(a.w);
  o[4]=f2bf(b.x); o[5]=f2bf(b.y); o[6]=f2bf(b.z); o[7]=f2bf(b.w);
  *(u16x8*)(dst + off) = o;
}

// ---------------- x -> vt[bh][d][n] bf16 (transposed V) ----------------
__global__ __launch_bounds__(256) void k_transpose_v(const float* __restrict__ x,
                                                     u16* __restrict__ vt) {
  __shared__ float ts[64][65];
  int nt = blockIdx.x;   // 0..31  (n tile of 64)
  int h  = blockIdx.y;   // 0..7
  int b  = blockIdx.z;   // 0..3
  int t = threadIdx.x;
  int n0 = nt * 64;
  int r16 = t >> 4;         // 0..15
  int c4  = (t & 15) * 4;   // 0..60
#pragma unroll
  for (int rep = 0; rep < 4; ++rep) {
    int n_loc = rep*16 + r16;
    float4 v = *(const float4*)(x + (size_t)(b*N_ + n0 + n_loc)*DIM_ + h*64 + c4);
    ts[n_loc][c4+0]=v.x; ts[n_loc][c4+1]=v.y; ts[n_loc][c4+2]=v.z; ts[n_loc][c4+3]=v.w;
  }
  __syncthreads();
#pragma unroll
  for (int rep = 0; rep < 4; ++rep) {
    int d_loc = rep*16 + r16;
    u16x4 o;
#pragma unroll
    for (int i = 0; i < 4; ++i) o[i] = f2bf(ts[c4+i][d_loc]);
    *(u16x4*)(vt + (size_t)((b*H_+h)*64 + d_loc)*N_ + n0 + c4) = o;
  }
}

// ---------------- projection GEMM: [8192x512] = xb @ W^T, store head-major ----------------
// grid (64 mtiles, 4 ntiles, 2 z[q|k]); 256 threads, 4 waves 2x2
__global__ __launch_bounds__(256) void k_gemm_qk(const u16* __restrict__ xb,
                                                 const u16* __restrict__ wqb,
                                                 const u16* __restrict__ wkb,
                                                 u16* __restrict__ qb,
                                                 u16* __restrict__ kb) {
  __shared__ __align__(16) u16 As[128*64];
  __shared__ __align__(16) u16 Bs[128*64];
  int mt = blockIdx.x, ntile = blockIdx.y, z = blockIdx.z;
  const u16* Bw = z ? wkb : wqb;
  u16* C = z ? kb : qb;
  float scale = z ? 1.0f : 0.125f;
  int tid = threadIdx.x, lane = tid & 63, w = tid >> 6;
  int wr = w >> 1, wc = w & 1;
  int lr = lane >> 3, lc8 = lane & 7;
  int l4 = lane >> 4, l15 = lane & 15;

  f32x4 acc[4][4] = {};

  const u16* Abase = xb + (size_t)(mt*128)*DIM_;
  const u16* Bbase = Bw + (size_t)(ntile*128)*DIM_;

  for (int kk = 0; kk < 8; ++kk) {
#pragma unroll
    for (int i = 0; i < 4; ++i) {
      int rowl = w*32 + i*8 + lr;
      int cbs = lc8 ^ (rowl & 7);
      gload_lds16(Abase + (size_t)rowl*DIM_ + kk*64 + cbs*8, As + (w*32 + i*8)*64);
      gload_lds16(Bbase + (size_t)rowl*DIM_ + kk*64 + cbs*8, Bs + (w*32 + i*8)*64);
    }
    __syncthreads();
#pragma unroll
    for (int kc = 0; kc < 2; ++kc) {
      bf16x8 af[4], bfr[4];
#pragma unroll
      for (int i = 0; i < 4; ++i) {
        int row = wr*64 + i*16 + l15;
        int cb = (kc*4 + l4) ^ (row & 7);
        af[i] = *(const bf16x8*)(As + row*64 + cb*8);
      }
#pragma unroll
      for (int j = 0; j < 4; ++j) {
        int row = wc*64 + j*16 + l15;
        int cb = (kc*4 + l4) ^ (row & 7);
        bfr[j] = *(const bf16x8*)(Bs + row*64 + cb*8);
      }
#pragma unroll
      for (int i = 0; i < 4; ++i)
#pragma unroll
        for (int j = 0; j < 4; ++j)
          acc[i][j] = __builtin_amdgcn_mfma_f32_16x16x32_bf16(af[i], bfr[j], acc[i][j], 0, 0, 0);
    }
    __syncthreads();
  }
  // store to head-major [bh][n][64]
#pragma unroll
  for (int i = 0; i < 4; ++i) {
#pragma unroll
    for (int j = 0; j < 4; ++j) {
#pragma unroll
      for (int r = 0; r < 4; ++r) {
        int m = mt*128 + wr*64 + i*16 + l4*4 + r;
        int o = ntile*128 + wc*64 + j*16 + l15;
        u16 v = f2bf(acc[i][j][r] * scale);
        C[(size_t)((m >> 11)*H_ + (o >> 6))*(N_*64) + (size_t)(m & (N_-1))*64 + (o & 63)] = v;
      }
    }
  }
}

// ---------------- attention: out = tanh(q k^T) v ----------------
// grid (16 qtiles, 32 bh); 256 threads, 4 waves (wave w owns S/O rows w*32..w*32+31)
__global__ __launch_bounds__(256) void k_attn(const u16* __restrict__ qb,
                                              const u16* __restrict__ kb,
                                              const u16* __restrict__ vt,
                                              float* __restrict__ out) {
  __shared__ __align__(16) u16 Qs[128*64];
  __shared__ __align__(16) u16 Ks[128*64];
  __shared__ __align__(16) u16 Vs[64*128];
  __shared__ __align__(16) u16 Ps[128*128];
  int qt = blockIdx.x;
  int bh = blockIdx.y;
  int tid = threadIdx.x, lane = tid & 63, w = tid >> 6;
  int lr = lane >> 3, lc8 = lane & 7;
  int l4 = lane >> 4, l15 = lane & 15;

  const u16* qbase = qb + (size_t)bh*N_*64 + (size_t)qt*128*64;
  const u16* kbase = kb + (size_t)bh*N_*64;
  const u16* vbase = vt + (size_t)bh*64*N_;

  // stage Q once
#pragma unroll
  for (int i = 0; i < 4; ++i) {
    int rowl = w*32 + i*8 + lr;
    int cbs = lc8 ^ (rowl & 7);
    gload_lds16(qbase + (size_t)rowl*64 + cbs*8, Qs + (w*32 + i*8)*64);
  }

  f32x4 acc_o[2][4] = {};

  for (int jt = 0; jt < 16; ++jt) {
    // stage K tile [128][64]
#pragma unroll
    for (int i = 0; i < 4; ++i) {
      int rowl = w*32 + i*8 + lr;
      int cbs = lc8 ^ (rowl & 7);
      gload_lds16(kbase + (size_t)(jt*128 + rowl)*64 + cbs*8, Ks + (w*32 + i*8)*64);
    }
    // stage V tile as [64 d][128 kv]
#pragma unroll
    for (int i = 0; i < 4; ++i) {
      int rowl = w*16 + i*4 + l4;
      int cbs = l15 ^ (rowl & 7);
      gload_lds16(vbase + (size_t)rowl*N_ + jt*128 + cbs*8, Vs + (w*16 + i*4)*128);
    }
    __syncthreads();

    // S = Q K^T for this wave's 32 rows
    f32x4 accs[2][8] = {};
#pragma unroll
    for (int kc = 0; kc < 2; ++kc) {
      bf16x8 aq[2], bk[8];
#pragma unroll
      for (int i = 0; i < 2; ++i) {
        int row = w*32 + i*16 + l15;
        int cb = (kc*4 + l4) ^ (row & 7);
        aq[i] = *(const bf16x8*)(Qs + row*64 + cb*8);
      }
#pragma unroll
      for (int j = 0; j < 8; ++j) {
        int row = j*16 + l15;
        int cb = (kc*4 + l4) ^ (row & 7);
        bk[j] = *(const bf16x8*)(Ks + row*64 + cb*8);
      }
#pragma unroll
      for (int i = 0; i < 2; ++i)
#pragma unroll
        for (int j = 0; j < 8; ++j)
          accs[i][j] = __builtin_amdgcn_mfma_f32_16x16x32_bf16(aq[i], bk[j], accs[i][j], 0, 0, 0);
    }

    // P = tanh(S) -> bf16 into swizzled per-wave rows of Ps
#pragma unroll
    for (int i = 0; i < 2; ++i) {
#pragma unroll
      for (int j = 0; j < 8; ++j) {
#pragma unroll
        for (int r = 0; r < 4; ++r) {
          int row = w*32 + i*16 + l4*4 + r;
          int col = j*16 + l15;
          float e = __builtin_amdgcn_exp2f(accs[i][j][r] * 2.8853900817779268f);
          float t = 1.0f - 2.0f * __builtin_amdgcn_rcpf(e + 1.0f);
          int byt = row*256 + ((col*2) ^ ((row & 7) << 4));
          *(u16*)((char*)Ps + byt) = f2bf(t);
        }
      }
    }

    // O += P V  (A from own Ps rows, B from Vs)
#pragma unroll
    for (int kc = 0; kc < 4; ++kc) {
      bf16x8 ap[2], bv[4];
#pragma unroll
      for (int i = 0; i < 2; ++i) {
        int row = w*32 + i*16 + l15;
        int cb = (kc*4 + l4) ^ (row & 7);
        ap[i] = *(const bf16x8*)((const char*)Ps + row*256 + cb*16);
      }
#pragma unroll
      for (int j = 0; j < 4; ++j) {
        int row = j*16 + l15;
        int cb = (kc*4 + l4) ^ (row & 7);
        bv[j] = *(const bf16x8*)((const char*)Vs + row*256 + cb*16);
      }
#pragma unroll
      for (int i = 0; i < 2; ++i)
#pragma unroll
        for (int j = 0; j < 4; ++j)
          acc_o[i][j] = __builtin_amdgcn_mfma_f32_16x16x32_bf16(ap[i], bv[j], acc_o[i][j], 0, 0, 0);
    }
    __syncthreads();
  }

  // epilogue: out[b][n][h*64+d] f32
  int b = bh >> 3, h = bh & 7;
#pragma unroll
  for (int i = 0; i < 2; ++i) {
#pragma unroll
    for (int j = 0; j < 4; ++j) {
#pragma unroll
      for (int r = 0; r < 4; ++r) {
        int n = qt*128 + w*32 + i*16 + l4*4 + r;
        int d = j*16 + l15;
        out[(size_t)(b*N_ + n)*DIM_ + h*64 + d] = acc_o[i][j][r];
      }
    }
  }
}

extern "C" void kernel_launch(void* const* d_in, const int* in_sizes, int n_in,
                              void* d_out, int out_size, void* d_ws, size_t ws_size,
                              hipStream_t stream) {
  const float* x  = (const float*)d_in[0];
  const float* Wq = (const float*)d_in[1];
  const float* Wk = (const float*)d_in[2];
  float* out = (float*)d_out;
  char* ws = (char*)d_ws;
  u16* xb  = (u16*)(ws);                      // 8192*512*2  = 8 MiB
  u16* wqb = (u16*)(ws + 8388608);            // 512 KiB
  u16* wkb = (u16*)(ws + 8912896);            // 512 KiB
  u16* qb  = (u16*)(ws + 9437184);            // 8 MiB  [bh][n][64]
  u16* kb  = (u16*)(ws + 17825792);           // 8 MiB
  u16* vt  = (u16*)(ws + 26214400);           // 8 MiB  [bh][d][n]

  k_convert_x<<<2048, 256, 0, stream>>>(x, xb);
  k_convert_w<<<256, 256, 0, stream>>>(Wq, Wk, wqb, wkb);
  k_transpose_v<<<dim3(32, 8, 4), 256, 0, stream>>>(x, vt);
  k_gemm_qk<<<dim3(64, 4, 2), 256, 0, stream>>>(xb, wqb, wkb, qb, kb);
  k_attn<<<dim3(16, 32), 256, 0, stream>>>(qb, kb, vt, out);
}